// Round 9
// baseline (162.546 us; speedup 1.0000x reference)
//
#include <hip/hip_runtime.h>

#define FEAT 128
#define NPB 50             // nodes per bin
#define NB 1000            // 50000/50 bins exactly
#define HB 500             // bins per scatter half
#define MAGIC50 85899346u  // ceil(2^32/50); exact floor-div for dd < 2^27
#define CELL 16            // uints per (bin,blk) cell: slot0=count, 15 data; one 64B line
#define CAP 48             // per-node bucket cap; Poisson(12.8): P(deg>=48) negligible
#define SBLK 256           // scatter writer-blocks per bin
#define CVB 512            // feat-convert blocks
#define SB_STRIDE 136      // LDS row stride: 128 + 8 pad shorts
#define GEMB 782           // ceil(50000/64) gemm tiles

typedef __attribute__((ext_vector_type(8))) short bhalf8;
typedef __attribute__((ext_vector_type(4))) float floatx4;

// HW packed f32->bf16 convert (RNE).
__device__ __forceinline__ unsigned int cvtpk(float lo, float hi) {
    unsigned int r;
    asm("v_cvt_pk_bf16_f32 %0, %1, %2" : "=v"(r) : "v"(lo), "v"(hi));
    return r;
}

__device__ __forceinline__ void acc8(float* a, uint4 v) {
    a[0] += __uint_as_float(v.x << 16);
    a[1] += __uint_as_float(v.x & 0xffff0000u);
    a[2] += __uint_as_float(v.y << 16);
    a[3] += __uint_as_float(v.y & 0xffff0000u);
    a[4] += __uint_as_float(v.z << 16);
    a[5] += __uint_as_float(v.z & 0xffff0000u);
    a[6] += __uint_as_float(v.w << 16);
    a[7] += __uint_as_float(v.w & 0xffff0000u);
}

// ================= D1: scatter-halves || FB convert || WB transpose =========
// blocks [0,1024):  scatter; block sb owns bins [half*HB, half*HB+HB),
//                   half = sb>>8, scans edge-slice (sb&255) with bin filter.
//                   LDS 32.5KB -> 4 blocks/CU merged with converts (R7 lesson:
//                   only merge roles with similar LDS footprints).
// blocks [1024,1536): feat f32 -> FB bf16
// block  1536:        W f32 -> WB bf16 transposed
__global__ __launch_bounds__(256, 4) void prep_kernel(
    const float* __restrict__ feat, const float* __restrict__ W,
    const int* __restrict__ edst, const int* __restrict__ esrc,
    unsigned short* __restrict__ FB, unsigned short* __restrict__ WB,
    unsigned int* __restrict__ binned, int nrows, int nE)
{
    __shared__ __align__(16) unsigned int lbin[HB * CELL];  // 32000 B
    __shared__ unsigned int cur32[HB / 4];                  // 125 packed cursors

    const int tid = threadIdx.x;

    if (blockIdx.x < 2 * SBLK) {
        // ---- scatter role ----
        const int sb   = blockIdx.x;
        const int blk  = sb & (SBLK - 1);
        const int half = sb >> 8;
        const unsigned int binBase = half * HB;

        for (int i = tid; i < HB / 4; i += 256) cur32[i] = 0u;
        __syncthreads();

        const int nE4 = nE >> 2;
        const int perBlk = (nE4 + SBLK - 1) / SBLK;   // 625
        const int gBeg = blk * perBlk;
        const int gEnd = min(gBeg + perBlk, nE4);

        for (int g = gBeg + tid; g < gEnd; g += 256) {
            int4 d = *(const int4*)&edst[g << 2];
            int4 s = *(const int4*)&esrc[g << 2];
            #pragma unroll
            for (int e = 0; e < 4; ++e) {
                int dd = (e == 0) ? d.x : (e == 1) ? d.y : (e == 2) ? d.z : d.w;
                int ss = (e == 0) ? s.x : (e == 1) ? s.y : (e == 2) ? s.z : s.w;
                unsigned int bin = __umulhi((unsigned int)dd, MAGIC50);
                unsigned int lb = bin - binBase;
                if (lb < HB) {
                    int local = dd - (int)bin * NPB;
                    const int sh = (lb & 3) * 8;
                    unsigned int old = atomicAdd(&cur32[lb >> 2], 1u << sh);
                    int slot = (int)((old >> sh) & 0xffu);
                    if (slot < CELL - 1)
                        lbin[lb * CELL + 1 + slot] =
                            ((unsigned int)local << 16) | (unsigned int)(ss & 0xffff);
                }
            }
        }
        if (blk == 0) {   // scalar tail per half (empty when nE % 4 == 0)
            for (int i = (nE4 << 2) + tid; i < nE; i += 256) {
                int dd = edst[i], ss = esrc[i];
                unsigned int bin = __umulhi((unsigned int)dd, MAGIC50);
                unsigned int lb = bin - binBase;
                if (lb < HB) {
                    int local = dd - (int)bin * NPB;
                    const int sh = (lb & 3) * 8;
                    unsigned int old = atomicAdd(&cur32[lb >> 2], 1u << sh);
                    int slot = (int)((old >> sh) & 0xffu);
                    if (slot < CELL - 1)
                        lbin[lb * CELL + 1 + slot] =
                            ((unsigned int)local << 16) | (unsigned int)(ss & 0xffff);
                }
            }
        }
        __syncthreads();

        for (int lb = tid; lb < HB; lb += 256) {
            unsigned int c = (cur32[lb >> 2] >> ((lb & 3) * 8)) & 0xffu;
            lbin[lb * CELL] = min(c, (unsigned int)(CELL - 1));
        }
        __syncthreads();

        // transposed flush: 4 lanes write one FULL 64B cell (no partial-line RFO)
        const int lane = tid & 63;
        const int wv   = tid >> 6;
        const int q    = lane & 3;
        for (int cg = wv * 16 + (lane >> 2); cg < HB; cg += 64) {
            uint4 v = *(const uint4*)&lbin[cg * CELL + q * 4];
            *(uint4*)&binned[((size_t)(binBase + cg) * SBLK + blk) * CELL + q * 4] = v;
        }
        return;
    }

    if (blockIdx.x < 2 * SBLK + CVB) {
        // ---- feat -> bf16 convert role ----
        const int cb = blockIdx.x - 2 * SBLK;
        const size_t total = (size_t)nrows * (FEAT / 8);
        for (size_t g = (size_t)cb * 256 + tid; g < total; g += (size_t)CVB * 256) {
            const float* fp = &feat[g * 8];
            float4 f0 = *(const float4*)fp;
            float4 f1 = *(const float4*)(fp + 4);
            uint4 p;
            p.x = cvtpk(f0.x, f0.y);
            p.y = cvtpk(f0.z, f0.w);
            p.z = cvtpk(f1.x, f1.y);
            p.w = cvtpk(f1.z, f1.w);
            *(uint4*)&FB[g * 8] = p;
        }
        return;
    }

    // ---- W -> bf16 transposed role (single block) ----
    for (int i = tid; i < 2048; i += 256) {
        int n  = i >> 4;
        int k8 = i & 15;
        float f[8];
        #pragma unroll
        for (int t = 0; t < 8; ++t) f[t] = W[(size_t)(k8 * 8 + t) * FEAT + n];
        uint4 p;
        p.x = cvtpk(f[0], f[1]);
        p.y = cvtpk(f[2], f[3]);
        p.z = cvtpk(f[4], f[5]);
        p.w = cvtpk(f[6], f[7]);
        *(uint4*)&WB[n * FEAT + k8 * 8] = p;
    }
}

// ================= D2: gather || gemm, interleaved 1:1, EQUAL LDS ==========
// R7's regression was LDS coupling (gemm's 34.8KB sB dragged gather to 20% occ).
// Here BOTH roles use only the gather's 22.4KB: the gemm reads B-fragments
// straight from the 32KB L1/L2-hot WB (form validated by R8's projection) and
// A-fragments from bf16 FB. 6 blocks/CU; gemm streaming fills the gather's
// scattered-request stalls.
__global__ __launch_bounds__(256, 6) void main_kernel(
    const unsigned short* __restrict__ FB, const unsigned short* __restrict__ WB,
    const unsigned int* __restrict__ binned, float* __restrict__ out, int nrows)
{
    __shared__ int lcnt[NPB];
    __shared__ unsigned short lbkt[NPB * CAP];        // 4800 B
    __shared__ unsigned short smean[64 * SB_STRIDE];  // 17408 B

    const int tid  = threadIdx.x;
    const int bid  = blockIdx.x;
    const int wave = tid >> 6;
    const int lane = tid & 63;
    const int m    = lane & 15;
    const int kg   = lane >> 4;

    bool isGather;
    int rid;
    if (bid < 2 * GEMB) { isGather = (bid & 1); rid = bid >> 1; }
    else                { isGather = true;      rid = GEMB + (bid - 2 * GEMB); }

    if (isGather) {
        // ---- gather role (R8-proven quarter-wave MLP form) ----
        const int bin = rid;

        for (int i = tid; i < NPB; i += 256) lcnt[i] = 0;
        __syncthreads();

        // rebin: contiguous 16KB strip, one 64B cell per thread
        {
            const unsigned int* cell = &binned[((size_t)bin * SBLK + tid) * CELL];
            const int cnt = (int)cell[0];
            for (int k = 0; k < cnt; ++k) {
                unsigned int u = cell[1 + k];
                int local = (int)(u >> 16);
                int slot = atomicAdd(&lcnt[local], 1);
                if (slot < CAP) lbkt[local * CAP + slot] = (unsigned short)(u & 0xffffu);
            }
        }
        __syncthreads();

        const int qw = tid >> 4;   // quarter-wave id 0..15
        const int cl = tid & 15;   // feats 8*cl .. 8*cl+7

        for (int l = qw; l < NPB; l += 16) {
            const int deg = min(lcnt[l], CAP);
            float acc[8];
            #pragma unroll
            for (int t = 0; t < 8; ++t) acc[t] = 0.f;

            const unsigned short* bkt = &lbkt[l * CAP];
            for (int j0 = 0; j0 < deg; j0 += 4) {
                int s0 = (int)bkt[j0];
                int s1 = (j0 + 1 < deg) ? (int)bkt[j0 + 1] : s0;
                int s2 = (j0 + 2 < deg) ? (int)bkt[j0 + 2] : s0;
                int s3 = (j0 + 3 < deg) ? (int)bkt[j0 + 3] : s0;
                uint4 v0 = *(const uint4*)&FB[(size_t)s0 * FEAT + cl * 8];
                uint4 v1 = *(const uint4*)&FB[(size_t)s1 * FEAT + cl * 8];
                uint4 v2 = *(const uint4*)&FB[(size_t)s2 * FEAT + cl * 8];
                uint4 v3 = *(const uint4*)&FB[(size_t)s3 * FEAT + cl * 8];
                if (j0 + 1 >= deg) v1 = make_uint4(0u, 0u, 0u, 0u);
                if (j0 + 2 >= deg) v2 = make_uint4(0u, 0u, 0u, 0u);
                if (j0 + 3 >= deg) v3 = make_uint4(0u, 0u, 0u, 0u);
                acc8(acc, v0);
                acc8(acc, v1);
                acc8(acc, v2);
                acc8(acc, v3);
            }

            const float inv = (deg > 0) ? (1.0f / (float)deg) : 0.0f;
            uint4 p;
            p.x = cvtpk(acc[0] * inv, acc[1] * inv);
            p.y = cvtpk(acc[2] * inv, acc[3] * inv);
            p.z = cvtpk(acc[4] * inv, acc[5] * inv);
            p.w = cvtpk(acc[6] * inv, acc[7] * inv);
            *(uint4*)&smean[l * SB_STRIDE + cl * 8] = p;
        }
        __syncthreads();

        // projection: smean @ W ; B-fragments from global WB (L1-hot 32KB)
        bhalf8 am[4];
        const int arow = wave * 16 + m;
        #pragma unroll
        for (int ks = 0; ks < 4; ++ks)
            am[ks] = *(bhalf8*)&smean[arow * SB_STRIDE + ks * 32 + kg * 8];

        floatx4 acc[8];
        #pragma unroll
        for (int nt = 0; nt < 8; ++nt) acc[nt] = (floatx4){0.f, 0.f, 0.f, 0.f};

        #pragma unroll
        for (int ks = 0; ks < 4; ++ks) {
            #pragma unroll
            for (int nt = 0; nt < 8; ++nt) {
                bhalf8 bb = *(const bhalf8*)&WB[(size_t)(nt * 16 + m) * FEAT + ks * 32 + kg * 8];
                acc[nt] = __builtin_amdgcn_mfma_f32_16x16x32_bf16(am[ks], bb, acc[nt], 0, 0, 0);
            }
        }

        const int lbase = wave * 16 + kg * 4;
        #pragma unroll
        for (int i = 0; i < 4; ++i) {
            int local = lbase + i;
            int node = bin * NPB + local;
            if (local < NPB && node < nrows) {
                #pragma unroll
                for (int nt = 0; nt < 8; ++nt)
                    out[(size_t)node * (2 * FEAT) + FEAT + nt * 16 + m] =
                        fmaxf(acc[nt][i], 0.f);
            }
        }
        return;
    }

    // ---- gemm role: out[:, :128] = relu(FB @ WB), no LDS staging ----
    const int bx = rid;
    const int row  = bx * 64 + wave * 16 + m;
    const int rowc = min(row, nrows - 1);
    bhalf8 afrag[4];
    {
        const unsigned short* ap = &FB[(size_t)rowc * FEAT + kg * 8];
        #pragma unroll
        for (int ks = 0; ks < 4; ++ks)
            afrag[ks] = *(const bhalf8*)&ap[ks * 32];
    }

    floatx4 acc[8];
    #pragma unroll
    for (int nt = 0; nt < 8; ++nt) acc[nt] = (floatx4){0.f, 0.f, 0.f, 0.f};

    #pragma unroll
    for (int ks = 0; ks < 4; ++ks) {
        #pragma unroll
        for (int nt = 0; nt < 8; ++nt) {
            bhalf8 bb = *(const bhalf8*)&WB[(size_t)(nt * 16 + m) * FEAT + ks * 32 + kg * 8];
            acc[nt] = __builtin_amdgcn_mfma_f32_16x16x32_bf16(afrag[ks], bb, acc[nt], 0, 0, 0);
        }
    }

    const int rbase = bx * 64 + wave * 16 + kg * 4;
    #pragma unroll
    for (int i = 0; i < 4; ++i) {
        int r = rbase + i;
        if (r < nrows) {
            #pragma unroll
            for (int nt = 0; nt < 8; ++nt)
                out[(size_t)r * (2 * FEAT) + nt * 16 + m] = fmaxf(acc[nt][i], 0.f);
        }
    }
}

extern "C" void kernel_launch(void* const* d_in, const int* in_sizes, int n_in,
                              void* d_out, int out_size, void* d_ws, size_t ws_size,
                              hipStream_t stream)
{
    const float* feat = (const float*)d_in[0];
    const float* W    = (const float*)d_in[1];
    const int* edst   = (const int*)d_in[2];
    const int* esrc   = (const int*)d_in[3];
    float* out        = (float*)d_out;

    const int N = in_sizes[0] / FEAT;   // 50000
    const int E = in_sizes[2];          // 640000

    char* ws = (char*)d_ws;
    unsigned short* FB = (unsigned short*)ws;               // N*128 bf16 = 12.8 MB
    size_t off = (size_t)N * FEAT * sizeof(unsigned short);
    off = (off + 63) & ~(size_t)63;
    unsigned int* binned = (unsigned int*)(ws + off);       // NB*SBLK*CELL uints = 16.4 MB
    off += (size_t)NB * SBLK * CELL * 4;
    off = (off + 63) & ~(size_t)63;
    unsigned short* WB = (unsigned short*)(ws + off);       // 128*128 bf16 = 32 KB
    off += (size_t)FEAT * FEAT * sizeof(unsigned short);

    // D1: scatter-halves (32.5KB LDS) || feat->FB || W->WB^T  — 4 blocks/CU
    prep_kernel<<<2 * SBLK + CVB + 1, 256, 0, stream>>>(
        feat, W, edst, esrc, FB, WB, binned, N, E);

    // D2: gather || gemm interleaved, both 22.4KB LDS — 6 blocks/CU
    main_kernel<<<NB + GEMB, 256, 0, stream>>>(FB, WB, binned, out, N);
}

// Round 10
// 133.937 us; speedup vs baseline: 1.2136x; 1.2136x over previous
//
#include <hip/hip_runtime.h>

#define FEAT 128
#define NPB 49             // nodes per bin
#define NB 1021            // ceil(50000/49) bins
#define MAGIC 87652394u    // ceil(2^32/49); exact floor-div for dst < 4e8
#define CELL 20            // uints per (bin,block) cell; Poisson(2.45): P(>=21)~2.5e-13
#define CAP 48             // per-node bucket cap; Poisson(12.8): 50000*P(deg>=48)~3e-8
#define SBLK 256           // scatter blocks (one per CU, dispatched first)
#define SB_STRIDE 136      // gemm LDS row stride: 128 + 8 pad shorts

typedef __attribute__((ext_vector_type(8))) short bhalf8;
typedef __attribute__((ext_vector_type(4))) float floatx4;

// HW packed f32->bf16 convert (RNE).
__device__ __forceinline__ unsigned int cvtpk(float lo, float hi) {
    unsigned int r;
    asm("v_cvt_pk_bf16_f32 %0, %1, %2" : "=v"(r) : "v"(lo), "v"(hi));
    return r;
}

__device__ __forceinline__ void acc8(float* a, uint4 v) {
    a[0] += __uint_as_float(v.x << 16);
    a[1] += __uint_as_float(v.x & 0xffff0000u);
    a[2] += __uint_as_float(v.y << 16);
    a[3] += __uint_as_float(v.y & 0xffff0000u);
    a[4] += __uint_as_float(v.z << 16);
    a[5] += __uint_as_float(v.z & 0xffff0000u);
    a[6] += __uint_as_float(v.w << 16);
    a[7] += __uint_as_float(v.w & 0xffff0000u);
}

// ---- ONE dispatch, two block roles (R4-proven 130.8us structure, verbatim):
//   blocks [0, SBLK)   : edge binning with LDS cursors only (ZERO device atomics)
//   blocks [SBLK, ...) : MFMA GEMM (P2 = bf16(feat@W); out[:,:128] = relu)
__global__ __launch_bounds__(256, 4) void fused_kernel(
    const float* __restrict__ feat, const float* __restrict__ W,
    unsigned short* __restrict__ P2, float* __restrict__ out, int nrows,
    const int* __restrict__ edst, const int* __restrict__ esrc,
    unsigned int* __restrict__ binned, unsigned char* __restrict__ cellcnt, int nE)
{
    __shared__ char smem[128 * SB_STRIDE * 2];  // 34816 B (gemm sB / scatter cursors)

    const int tid = threadIdx.x;

    if (blockIdx.x < SBLK) {
        // ================= scatter role =================
        int* cur = (int*)smem;                 // [NB] cursors
        for (int i = tid; i < NB; i += 256) cur[i] = 0;
        __syncthreads();

        const int blk = blockIdx.x;
        const int nE4 = nE >> 2;
        const int perBlk = (nE4 + SBLK - 1) / SBLK;   // 625
        const int gBeg = blk * perBlk;
        const int gEnd = min(gBeg + perBlk, nE4);

        for (int g = gBeg + tid; g < gEnd; g += 256) {
            int4 d = *(const int4*)&edst[g << 2];
            int4 s = *(const int4*)&esrc[g << 2];
            #pragma unroll
            for (int e = 0; e < 4; ++e) {
                int dd = (e == 0) ? d.x : (e == 1) ? d.y : (e == 2) ? d.z : d.w;
                int ss = (e == 0) ? s.x : (e == 1) ? s.y : (e == 2) ? s.z : s.w;
                unsigned int bin = __umulhi((unsigned int)dd, MAGIC);
                int local = dd - (int)bin * NPB;
                int slot = atomicAdd(&cur[bin], 1);            // LDS atomic
                if (slot < CELL)
                    binned[((size_t)bin * SBLK + blk) * CELL + slot] =
                        ((unsigned int)local << 16) | (unsigned int)(ss & 0xffff);
            }
        }
        // scalar tail (nE % 4 == 0 here; harmless)
        if (blk == 0) {
            for (int i = (nE4 << 2) + tid; i < nE; i += 256) {
                int dd = edst[i], ss = esrc[i];
                unsigned int bin = __umulhi((unsigned int)dd, MAGIC);
                int local = dd - (int)bin * NPB;
                int slot = atomicAdd(&cur[bin], 1);
                if (slot < CELL)
                    binned[((size_t)bin * SBLK + blk) * CELL + slot] =
                        ((unsigned int)local << 16) | (unsigned int)(ss & 0xffff);
            }
        }
        __syncthreads();
        for (int i = tid; i < NB; i += 256)
            cellcnt[(size_t)i * SBLK + blk] = (unsigned char)min(cur[i], CELL);
        return;
    }

    // ================= gemm role (proven R7/R9 structure) =================
    unsigned short* sB = (unsigned short*)smem;
    const int bx   = blockIdx.x - SBLK;
    const int wave = tid >> 6;
    const int lane = tid & 63;
    const int m    = lane & 15;   // A row / C col
    const int kg   = lane >> 4;   // k-group 0..3

    // stage W -> LDS transposed bf16: sB[n*SB_STRIDE + k] = bf16(W[k*128+n])
    for (int i = tid; i < 2048; i += 256) {
        int n  = i & 127;
        int kc = i >> 7;
        const float* wp = &W[(size_t)(kc * 8) * FEAT + n];
        float f[8];
        #pragma unroll
        for (int t = 0; t < 8; ++t) f[t] = wp[(size_t)t * FEAT];
        uint4 p;
        p.x = cvtpk(f[0], f[1]);
        p.y = cvtpk(f[2], f[3]);
        p.z = cvtpk(f[4], f[5]);
        p.w = cvtpk(f[6], f[7]);
        *(uint4*)&sB[n * SB_STRIDE + kc * 8] = p;
    }

    const int row  = bx * 64 + wave * 16 + m;
    const int rowc = min(row, nrows - 1);
    bhalf8 afrag[4];
    {
        const float* ap = &feat[(size_t)rowc * FEAT + kg * 8];
        #pragma unroll
        for (int ks = 0; ks < 4; ++ks) {
            float4 f0 = *(const float4*)&ap[ks * 32];
            float4 f1 = *(const float4*)&ap[ks * 32 + 4];
            union { bhalf8 v; unsigned int u[4]; } a;
            a.u[0] = cvtpk(f0.x, f0.y);
            a.u[1] = cvtpk(f0.z, f0.w);
            a.u[2] = cvtpk(f1.x, f1.y);
            a.u[3] = cvtpk(f1.z, f1.w);
            afrag[ks] = a.v;
        }
    }

    __syncthreads();

    floatx4 acc[8];
    #pragma unroll
    for (int nt = 0; nt < 8; ++nt) acc[nt] = (floatx4){0.f, 0.f, 0.f, 0.f};

    #pragma unroll
    for (int ks = 0; ks < 4; ++ks) {
        #pragma unroll
        for (int nt = 0; nt < 8; ++nt) {
            bhalf8 b = *(bhalf8*)&sB[(nt * 16 + m) * SB_STRIDE + ks * 32 + kg * 8];
            acc[nt] = __builtin_amdgcn_mfma_f32_16x16x32_bf16(afrag[ks], b, acc[nt], 0, 0, 0);
        }
    }

    // epilogue: C/D layout col=lane&15, row=(lane>>4)*4+i
    const int rbase = bx * 64 + wave * 16 + kg * 4;
    #pragma unroll
    for (int i = 0; i < 4; ++i) {
        int r = rbase + i;
        if (r < nrows) {
            #pragma unroll
            for (int nt = 0; nt < 8; nt += 2) {
                float v0 = acc[nt][i];
                float v1 = acc[nt + 1][i];
                int c = nt * 16 + m;
                out[(size_t)r * (2 * FEAT) + c]      = fmaxf(v0, 0.f);
                out[(size_t)r * (2 * FEAT) + c + 16] = fmaxf(v1, 0.f);
                unsigned int pk = cvtpk(v0, v1);
                P2[(size_t)r * FEAT + c]      = (unsigned short)(pk & 0xffffu);
                P2[(size_t)r * FEAT + c + 16] = (unsigned short)(pk >> 16);
            }
        }
    }
}

// ---- aggregate: one block per bin, QUARTER-WAVE per node (R8-proven form).
// Gathers projected P2 rows -> mean -> relu -> out[:,128:] directly: NO
// projection MFMA, no smean, no WB. LDS = 4.9KB; __launch_bounds__(256,8)
// = 32 waves/CU (2x R4's aggregate). Lane cl owns feats 8cl..8cl+7 in
// registers; edges in batches of 4 independent prefetched loads (no shfl
// chains, ~4x in-flight loads vs the R4 shfl form).
__global__ __launch_bounds__(256, 8) void aggregate_kernel(
    const unsigned short* __restrict__ P2, const unsigned int* __restrict__ binned,
    const unsigned char* __restrict__ cellcnt, float* __restrict__ out, int n)
{
    __shared__ int lcnt[NPB];
    __shared__ unsigned short lbkt[NPB * CAP];   // 4704 B

    const int bin = blockIdx.x;
    const int tid = threadIdx.x;

    for (int i = tid; i < NPB; i += 256) lcnt[i] = 0;
    __syncthreads();

    // rebin this bin's cells (contiguous 20KB strip) into per-node LDS buckets
    {
        const int cnt = (tid < SBLK) ? (int)cellcnt[(size_t)bin * SBLK + tid] : 0;
        const size_t base = ((size_t)bin * SBLK + tid) * CELL;
        for (int k = 0; k < cnt; ++k) {
            unsigned int u = binned[base + k];
            int local = (int)(u >> 16);
            int slot = atomicAdd(&lcnt[local], 1);            // LDS atomic
            if (slot < CAP) lbkt[local * CAP + slot] = (unsigned short)(u & 0xffffu);
        }
    }
    __syncthreads();

    const int qw = tid >> 4;   // quarter-wave id 0..15
    const int cl = tid & 15;   // feats 8*cl .. 8*cl+7

    for (int l = qw; l < NPB; l += 16) {
        const int node = bin * NPB + l;
        if (node >= n) continue;
        const int deg = min(lcnt[l], CAP);

        float acc[8];
        #pragma unroll
        for (int t = 0; t < 8; ++t) acc[t] = 0.f;

        const unsigned short* bkt = &lbkt[l * CAP];
        for (int j0 = 0; j0 < deg; j0 += 4) {
            // 4 independent prefetched row-loads (tail re-loads s0, zeroed)
            int s0 = (int)bkt[j0];
            int s1 = (j0 + 1 < deg) ? (int)bkt[j0 + 1] : s0;
            int s2 = (j0 + 2 < deg) ? (int)bkt[j0 + 2] : s0;
            int s3 = (j0 + 3 < deg) ? (int)bkt[j0 + 3] : s0;
            uint4 v0 = *(const uint4*)&P2[(size_t)s0 * FEAT + cl * 8];
            uint4 v1 = *(const uint4*)&P2[(size_t)s1 * FEAT + cl * 8];
            uint4 v2 = *(const uint4*)&P2[(size_t)s2 * FEAT + cl * 8];
            uint4 v3 = *(const uint4*)&P2[(size_t)s3 * FEAT + cl * 8];
            if (j0 + 1 >= deg) v1 = make_uint4(0u, 0u, 0u, 0u);
            if (j0 + 2 >= deg) v2 = make_uint4(0u, 0u, 0u, 0u);
            if (j0 + 3 >= deg) v3 = make_uint4(0u, 0u, 0u, 0u);
            acc8(acc, v0);
            acc8(acc, v1);
            acc8(acc, v2);
            acc8(acc, v3);
        }

        const float inv = (deg > 0) ? (1.0f / (float)deg) : 0.0f;
        float4 r0 = make_float4(fmaxf(acc[0] * inv, 0.f), fmaxf(acc[1] * inv, 0.f),
                                fmaxf(acc[2] * inv, 0.f), fmaxf(acc[3] * inv, 0.f));
        float4 r1 = make_float4(fmaxf(acc[4] * inv, 0.f), fmaxf(acc[5] * inv, 0.f),
                                fmaxf(acc[6] * inv, 0.f), fmaxf(acc[7] * inv, 0.f));
        float* op = &out[(size_t)node * (2 * FEAT) + FEAT + cl * 8];
        *(float4*)op = r0;
        *(float4*)(op + 4) = r1;
    }
}

extern "C" void kernel_launch(void* const* d_in, const int* in_sizes, int n_in,
                              void* d_out, int out_size, void* d_ws, size_t ws_size,
                              hipStream_t stream)
{
    const float* feat = (const float*)d_in[0];
    const float* W    = (const float*)d_in[1];
    const int* edst   = (const int*)d_in[2];
    const int* esrc   = (const int*)d_in[3];
    float* out        = (float*)d_out;

    const int N = in_sizes[0] / FEAT;   // 50000
    const int E = in_sizes[2];          // 640000

    char* ws = (char*)d_ws;
    unsigned short* P2 = (unsigned short*)ws;               // N*128 bf16 = 12.8 MB
    size_t off = (size_t)N * FEAT * sizeof(unsigned short);
    off = (off + 15) & ~(size_t)15;
    unsigned int* binned = (unsigned int*)(ws + off);       // NB*SBLK*CELL uints ~ 20.9 MB
    off += (size_t)NB * SBLK * CELL * 4;
    off = (off + 15) & ~(size_t)15;
    unsigned char* cellcnt = (unsigned char*)(ws + off);    // NB*SBLK bytes ~ 261 KB
    off += (size_t)NB * SBLK;

    // 1. fused dispatch: LDS-cursor binning (no device atomics) || MFMA gemm
    const int gemmBlocks = (N + 63) / 64;
    fused_kernel<<<SBLK + gemmBlocks, 256, 0, stream>>>(
        feat, W, P2, out, N, edst, esrc, binned, cellcnt, E);

    // 2. per-bin rebin + quarter-wave P2-mean + relu (32 waves/CU)
    aggregate_kernel<<<NB, 256, 0, stream>>>(P2, binned, cellcnt, out, N);
}

// Round 11
// 124.036 us; speedup vs baseline: 1.3105x; 1.0798x over previous
//
#include <hip/hip_runtime.h>

#define FEAT 128
#define NPB 50             // nodes per bin
#define NB 1000            // 50000/50 bins exactly
#define MAGIC50 85899346u  // ceil(2^32/50); exact floor-div for dd < 2^27
#define CELL 16            // uints per (bin,blk) cell: slot0=count, 15 data; one 64B line
#define CAP 48             // per-node bucket cap
#define SBLK 256           // scatter blocks (1 per CU)
#define SB_STRIDE 136      // gemm LDS row stride: 128 + 8 pad shorts

typedef __attribute__((ext_vector_type(8))) short bhalf8;
typedef __attribute__((ext_vector_type(4))) float floatx4;

// HW packed f32->bf16 convert (RNE).
__device__ __forceinline__ unsigned int cvtpk(float lo, float hi) {
    unsigned int r;
    asm("v_cvt_pk_bf16_f32 %0, %1, %2" : "=v"(r) : "v"(lo), "v"(hi));
    return r;
}

__device__ __forceinline__ void acc8(float* a, uint4 v) {
    a[0] += __uint_as_float(v.x << 16);
    a[1] += __uint_as_float(v.x & 0xffff0000u);
    a[2] += __uint_as_float(v.y << 16);
    a[3] += __uint_as_float(v.y & 0xffff0000u);
    a[4] += __uint_as_float(v.z << 16);
    a[5] += __uint_as_float(v.z & 0xffff0000u);
    a[6] += __uint_as_float(v.w << 16);
    a[7] += __uint_as_float(v.w & 0xffff0000u);
}

// ---- ONE dispatch, two roles (R4 structure + R8's LDS-staged scatter):
//   blocks [0, SBLK)   : edge binning fully in LDS, transposed FULL-LINE flush
//                        (was: 640k scattered 4B stores = divergent RFO, ~25-30us;
//                         now: 16.4MB of coalesced-per-cell 64B writes, ~8-10us)
//   blocks [SBLK, ...) : MFMA GEMM (P2 = bf16(feat@W); out[:,:128] = relu)
// Cost: 65KB LDS -> 2 blocks/CU for the gemm role too (8 waves/CU). Accepted:
// gemm is a one-shot streaming tile; scatter gain >> gemm latency-hiding loss.
__global__ __launch_bounds__(256, 2) void fused_kernel(
    const float* __restrict__ feat, const float* __restrict__ W,
    unsigned short* __restrict__ P2, float* __restrict__ out, int nrows,
    const int* __restrict__ edst, const int* __restrict__ esrc,
    unsigned int* __restrict__ binned, int nE)
{
    __shared__ __align__(16) char smem[NB * CELL * 4 + (NB / 4) * 4];  // 65000 B

    const int tid = threadIdx.x;

    if (blockIdx.x < SBLK) {
        // ================= scatter role (R8-K0 proven form) =================
        unsigned int* lbin  = (unsigned int*)smem;              // [NB*CELL]
        unsigned int* cur32 = (unsigned int*)(smem + NB * CELL * 4); // packed u8 x4

        const int blk = blockIdx.x;
        for (int i = tid; i < NB / 4; i += 256) cur32[i] = 0u;
        __syncthreads();

        const int nE4 = nE >> 2;
        const int perBlk = (nE4 + SBLK - 1) / SBLK;   // 625
        const int gBeg = blk * perBlk;
        const int gEnd = min(gBeg + perBlk, nE4);

        for (int g = gBeg + tid; g < gEnd; g += 256) {
            int4 d = *(const int4*)&edst[g << 2];
            int4 s = *(const int4*)&esrc[g << 2];
            #pragma unroll
            for (int e = 0; e < 4; ++e) {
                int dd = (e == 0) ? d.x : (e == 1) ? d.y : (e == 2) ? d.z : d.w;
                int ss = (e == 0) ? s.x : (e == 1) ? s.y : (e == 2) ? s.z : s.w;
                unsigned int bin = __umulhi((unsigned int)dd, MAGIC50);
                int local = dd - (int)bin * NPB;
                const int sh = (bin & 3) * 8;
                unsigned int old = atomicAdd(&cur32[bin >> 2], 1u << sh);
                int slot = (int)((old >> sh) & 0xffu);
                if (slot < CELL - 1)
                    lbin[bin * CELL + 1 + slot] =
                        ((unsigned int)local << 16) | (unsigned int)(ss & 0xffff);
            }
        }
        if (blk == 0) {   // scalar tail (empty when nE % 4 == 0)
            for (int i = (nE4 << 2) + tid; i < nE; i += 256) {
                int dd = edst[i], ss = esrc[i];
                unsigned int bin = __umulhi((unsigned int)dd, MAGIC50);
                int local = dd - (int)bin * NPB;
                const int sh = (bin & 3) * 8;
                unsigned int old = atomicAdd(&cur32[bin >> 2], 1u << sh);
                int slot = (int)((old >> sh) & 0xffu);
                if (slot < CELL - 1)
                    lbin[bin * CELL + 1 + slot] =
                        ((unsigned int)local << 16) | (unsigned int)(ss & 0xffff);
            }
        }
        __syncthreads();

        // embed counts in slot 0
        for (int bin = tid; bin < NB; bin += 256) {
            unsigned int c = (cur32[bin >> 2] >> ((bin & 3) * 8)) & 0xffu;
            lbin[bin * CELL] = min(c, (unsigned int)(CELL - 1));
        }
        __syncthreads();

        // transposed flush: 4 lanes write one FULL 64B cell to [bin][blk][CELL]
        const int lane = tid & 63;
        const int wv   = tid >> 6;
        const int q    = lane & 3;
        for (int cg = wv * 16 + (lane >> 2); cg < NB; cg += 64) {
            uint4 v = *(const uint4*)&lbin[cg * CELL + q * 4];
            *(uint4*)&binned[((size_t)cg * SBLK + blk) * CELL + q * 4] = v;
        }
        return;
    }

    // ================= gemm role (R4-proven, unchanged) =================
    unsigned short* sB = (unsigned short*)smem;
    const int bx   = blockIdx.x - SBLK;
    const int wave = tid >> 6;
    const int lane = tid & 63;
    const int m    = lane & 15;   // A row / C col
    const int kg   = lane >> 4;   // k-group 0..3

    // stage W -> LDS transposed bf16: sB[n*SB_STRIDE + k] = bf16(W[k*128+n])
    for (int i = tid; i < 2048; i += 256) {
        int n  = i & 127;
        int kc = i >> 7;
        const float* wp = &W[(size_t)(kc * 8) * FEAT + n];
        float f[8];
        #pragma unroll
        for (int t = 0; t < 8; ++t) f[t] = wp[(size_t)t * FEAT];
        uint4 p;
        p.x = cvtpk(f[0], f[1]);
        p.y = cvtpk(f[2], f[3]);
        p.z = cvtpk(f[4], f[5]);
        p.w = cvtpk(f[6], f[7]);
        *(uint4*)&sB[n * SB_STRIDE + kc * 8] = p;
    }

    const int row  = bx * 64 + wave * 16 + m;
    const int rowc = min(row, nrows - 1);
    bhalf8 afrag[4];
    {
        const float* ap = &feat[(size_t)rowc * FEAT + kg * 8];
        #pragma unroll
        for (int ks = 0; ks < 4; ++ks) {
            float4 f0 = *(const float4*)&ap[ks * 32];
            float4 f1 = *(const float4*)&ap[ks * 32 + 4];
            union { bhalf8 v; unsigned int u[4]; } a;
            a.u[0] = cvtpk(f0.x, f0.y);
            a.u[1] = cvtpk(f0.z, f0.w);
            a.u[2] = cvtpk(f1.x, f1.y);
            a.u[3] = cvtpk(f1.z, f1.w);
            afrag[ks] = a.v;
        }
    }

    __syncthreads();

    floatx4 acc[8];
    #pragma unroll
    for (int nt = 0; nt < 8; ++nt) acc[nt] = (floatx4){0.f, 0.f, 0.f, 0.f};

    #pragma unroll
    for (int ks = 0; ks < 4; ++ks) {
        #pragma unroll
        for (int nt = 0; nt < 8; ++nt) {
            bhalf8 b = *(bhalf8*)&sB[(nt * 16 + m) * SB_STRIDE + ks * 32 + kg * 8];
            acc[nt] = __builtin_amdgcn_mfma_f32_16x16x32_bf16(afrag[ks], b, acc[nt], 0, 0, 0);
        }
    }

    // epilogue: C/D layout col=lane&15, row=(lane>>4)*4+i
    const int rbase = bx * 64 + wave * 16 + kg * 4;
    #pragma unroll
    for (int i = 0; i < 4; ++i) {
        int r = rbase + i;
        if (r < nrows) {
            #pragma unroll
            for (int nt = 0; nt < 8; nt += 2) {
                float v0 = acc[nt][i];
                float v1 = acc[nt + 1][i];
                int c = nt * 16 + m;
                out[(size_t)r * (2 * FEAT) + c]      = fmaxf(v0, 0.f);
                out[(size_t)r * (2 * FEAT) + c + 16] = fmaxf(v1, 0.f);
                unsigned int pk = cvtpk(v0, v1);
                P2[(size_t)r * FEAT + c]      = (unsigned short)(pk & 0xffffu);
                P2[(size_t)r * FEAT + c + 16] = (unsigned short)(pk >> 16);
            }
        }
    }
}

// ---- aggregate: one block per bin, quarter-wave per node; rebin reads a
// CONTIGUOUS 16KB strip (counts in cell slot 0 — no cellcnt array).
// LDS ~5KB, __launch_bounds__(256,8) = 32 waves/CU.
__global__ __launch_bounds__(256, 8) void aggregate_kernel(
    const unsigned short* __restrict__ P2, const unsigned int* __restrict__ binned,
    float* __restrict__ out, int n)
{
    __shared__ int lcnt[NPB];
    __shared__ unsigned short lbkt[NPB * CAP];   // 4800 B

    const int bin = blockIdx.x;
    const int tid = threadIdx.x;

    for (int i = tid; i < NPB; i += 256) lcnt[i] = 0;
    __syncthreads();

    // rebin: one 64B cell per thread from the contiguous strip
    {
        const unsigned int* cell = &binned[((size_t)bin * SBLK + tid) * CELL];
        const int cnt = (int)cell[0];
        for (int k = 0; k < cnt; ++k) {
            unsigned int u = cell[1 + k];
            int local = (int)(u >> 16);
            int slot = atomicAdd(&lcnt[local], 1);
            if (slot < CAP) lbkt[local * CAP + slot] = (unsigned short)(u & 0xffffu);
        }
    }
    __syncthreads();

    const int qw = tid >> 4;   // quarter-wave id 0..15
    const int cl = tid & 15;   // feats 8*cl .. 8*cl+7

    for (int l = qw; l < NPB; l += 16) {
        const int node = bin * NPB + l;
        if (node >= n) continue;
        const int deg = min(lcnt[l], CAP);

        float acc[8];
        #pragma unroll
        for (int t = 0; t < 8; ++t) acc[t] = 0.f;

        const unsigned short* bkt = &lbkt[l * CAP];
        for (int j0 = 0; j0 < deg; j0 += 4) {
            int s0 = (int)bkt[j0];
            int s1 = (j0 + 1 < deg) ? (int)bkt[j0 + 1] : s0;
            int s2 = (j0 + 2 < deg) ? (int)bkt[j0 + 2] : s0;
            int s3 = (j0 + 3 < deg) ? (int)bkt[j0 + 3] : s0;
            uint4 v0 = *(const uint4*)&P2[(size_t)s0 * FEAT + cl * 8];
            uint4 v1 = *(const uint4*)&P2[(size_t)s1 * FEAT + cl * 8];
            uint4 v2 = *(const uint4*)&P2[(size_t)s2 * FEAT + cl * 8];
            uint4 v3 = *(const uint4*)&P2[(size_t)s3 * FEAT + cl * 8];
            if (j0 + 1 >= deg) v1 = make_uint4(0u, 0u, 0u, 0u);
            if (j0 + 2 >= deg) v2 = make_uint4(0u, 0u, 0u, 0u);
            if (j0 + 3 >= deg) v3 = make_uint4(0u, 0u, 0u, 0u);
            acc8(acc, v0);
            acc8(acc, v1);
            acc8(acc, v2);
            acc8(acc, v3);
        }

        const float inv = (deg > 0) ? (1.0f / (float)deg) : 0.0f;
        float4 r0 = make_float4(fmaxf(acc[0] * inv, 0.f), fmaxf(acc[1] * inv, 0.f),
                                fmaxf(acc[2] * inv, 0.f), fmaxf(acc[3] * inv, 0.f));
        float4 r1 = make_float4(fmaxf(acc[4] * inv, 0.f), fmaxf(acc[5] * inv, 0.f),
                                fmaxf(acc[6] * inv, 0.f), fmaxf(acc[7] * inv, 0.f));
        float* op = &out[(size_t)node * (2 * FEAT) + FEAT + cl * 8];
        *(float4*)op = r0;
        *(float4*)(op + 4) = r1;
    }
}

extern "C" void kernel_launch(void* const* d_in, const int* in_sizes, int n_in,
                              void* d_out, int out_size, void* d_ws, size_t ws_size,
                              hipStream_t stream)
{
    const float* feat = (const float*)d_in[0];
    const float* W    = (const float*)d_in[1];
    const int* edst   = (const int*)d_in[2];
    const int* esrc   = (const int*)d_in[3];
    float* out        = (float*)d_out;

    const int N = in_sizes[0] / FEAT;   // 50000
    const int E = in_sizes[2];          // 640000

    char* ws = (char*)d_ws;
    unsigned short* P2 = (unsigned short*)ws;               // N*128 bf16 = 12.8 MB
    size_t off = (size_t)N * FEAT * sizeof(unsigned short);
    off = (off + 63) & ~(size_t)63;
    unsigned int* binned = (unsigned int*)(ws + off);       // NB*SBLK*CELL*4 = 16.4 MB
    off += (size_t)NB * SBLK * CELL * 4;

    // 1. fused: LDS-staged binning (full-line transposed flush) || MFMA gemm
    const int gemmBlocks = (N + 63) / 64;
    fused_kernel<<<SBLK + gemmBlocks, 256, 0, stream>>>(
        feat, W, P2, out, N, edst, esrc, binned, E);

    // 2. per-bin contiguous rebin + quarter-wave P2-mean + relu
    aggregate_kernel<<<NB, 256, 0, stream>>>(P2, binned, out, N);
}